// Round 3
// baseline (211.033 us; speedup 1.0000x reference)
//
#include <hip/hip_runtime.h>
#include <hip/hip_bf16.h>

// Swin3D MHSA: B=256 windows, N=392 tokens, DIM=128, H=4 heads, dh=32.
// R3: W pre-converted to bf16 once (K0); qkv & proj become barrier-free,
//     LDS-free streaming MFMA GEMMs (A frags from global, W frags from L2).
//     Attention kernel unchanged from R2 (swapped-QK^T, lane-local softmax).

typedef __attribute__((ext_vector_type(8))) short bf16x8;
typedef __attribute__((ext_vector_type(4))) float f32x4;
typedef __attribute__((ext_vector_type(4))) short s16x4;
typedef __attribute__((ext_vector_type(2))) unsigned int u32x2;

#define NTOK 392
#define NN (NTOK * NTOK)   // 153664
#define TABLE 2535         // 15*13*13
#define SCALE 0.17677669529663689f  // 1/sqrt(32)

__device__ __forceinline__ unsigned short f2bf(float f) {
  union { float f; unsigned u; } v; v.f = f;
  unsigned r = v.u + 0x7FFFu + ((v.u >> 16) & 1u);
  return (unsigned short)(r >> 16);
}
__device__ __forceinline__ float b2f(short s) {
  union { unsigned u; float f; } v;
  v.u = ((unsigned)(unsigned short)s) << 16;
  return v.f;
}
__device__ __forceinline__ unsigned pk2(float lo, float hi) {
  return (unsigned)f2bf(lo) | ((unsigned)f2bf(hi) << 16);
}

// ---------------- K0: one-time weight conversion f32 -> bf16 ----------------
__global__ __launch_bounds__(256) void wcvt_kernel(
    const float* __restrict__ Wqkv, const float* __restrict__ Wp,
    unsigned short* __restrict__ wqbf, unsigned short* __restrict__ wpbf) {
  int g = blockIdx.x * 256 + threadIdx.x;  // 16384 threads x 4 elems
  const float* src; unsigned short* dst; int off;
  if (g < 12288) { src = Wqkv; dst = wqbf; off = g * 4; }
  else           { src = Wp;   dst = wpbf; off = (g - 12288) * 4; }
  f32x4 v = *(const f32x4*)(src + off);
  s16x4 o;
  o[0] = (short)f2bf(v[0]); o[1] = (short)f2bf(v[1]);
  o[2] = (short)f2bf(v[2]); o[3] = (short)f2bf(v[3]);
  *(s16x4*)(dst + off) = o;
}

// ---------------- K1: bias in MFMA lane layout ----------------
__global__ __launch_bounds__(256) void biaspre_kernel(
    const float* __restrict__ rpb, const int* __restrict__ relidx,
    unsigned short* __restrict__ biaspre) {
  int g = blockIdx.x * 256 + threadIdx.x;  // 4*25*25*256 = 640000
  if (g >= 640000) return;
  int r = g & 3, lane = (g >> 2) & 63;
  int t = g >> 8;
  int jt = t % 25; int t2 = t / 25;
  int rb = t2 % 25; int h = t2 / 25;
  int q = rb * 16 + (lane & 15); if (q > 391) q = 391;
  int k = jt * 16 + (lane >> 4) * 4 + r; if (k > 391) k = 391;
  int f = q * (NTOK * 4) + k * 4 + h;   // raw (n,n,H) reshape quirk
  int hs = f / NN; int p = f - hs * NN;
  biaspre[g] = f2bf(rpb[hs * TABLE + relidx[p]]);
}

// ---------------- K2: QKV projection — streaming, no LDS, no barriers ------
__global__ __launch_bounds__(256, 3) void qkv_kernel(
    const float* __restrict__ hidden, const unsigned short* __restrict__ wqbf,
    const float* __restrict__ bqkv,
    unsigned short* __restrict__ qbuf, unsigned short* __restrict__ kbuf,
    unsigned short* __restrict__ vtbuf) {
  const int tid = threadIdx.x;
  const int w = tid >> 6, lane = tid & 63, l15 = lane & 15, lhi = lane >> 4;
  const int row0 = blockIdx.x * 128 + w * 32;  // wave covers 32 token rows

  // A fragments: 2 m-subtiles x 4 k-steps, converted once, reused 3x
  bf16x8 af[2][4];
#pragma unroll
  for (int m = 0; m < 2; ++m)
#pragma unroll
    for (int kk = 0; kk < 4; ++kk) {
      const float* ap =
          hidden + ((size_t)(row0 + m * 16 + l15)) * 128 + kk * 32 + lhi * 8;
      f32x4 lo = *(const f32x4*)ap;
      f32x4 hi = *(const f32x4*)(ap + 4);
      bf16x8 a;
      a[0] = (short)f2bf(lo[0]); a[1] = (short)f2bf(lo[1]);
      a[2] = (short)f2bf(lo[2]); a[3] = (short)f2bf(lo[3]);
      a[4] = (short)f2bf(hi[0]); a[5] = (short)f2bf(hi[1]);
      a[6] = (short)f2bf(hi[2]); a[7] = (short)f2bf(hi[3]);
      af[m][kk] = a;
    }

  for (int s = 0; s < 3; ++s) {
    f32x4 acc[2][8];
#pragma unroll
    for (int m = 0; m < 2; ++m)
#pragma unroll
      for (int jt = 0; jt < 8; ++jt) acc[m][jt] = 0.0f;
#pragma unroll
    for (int kk = 0; kk < 4; ++kk) {
#pragma unroll
      for (int jt = 0; jt < 8; ++jt) {
        bf16x8 wf = *(const bf16x8*)(
            wqbf + ((size_t)(s * 128 + jt * 16 + l15)) * 128 + kk * 32 + lhi * 8);
        acc[0][jt] = __builtin_amdgcn_mfma_f32_16x16x32_bf16(af[0][kk], wf, acc[0][jt], 0, 0, 0);
        acc[1][jt] = __builtin_amdgcn_mfma_f32_16x16x32_bf16(af[1][kk], wf, acc[1][jt], 0, 0, 0);
      }
    }
#pragma unroll
    for (int m = 0; m < 2; ++m) {
      const int t0 = row0 + m * 16 + lhi * 4;  // mult of 4; stays in one window
      const int bb = t0 / 392;
      const int nn0 = t0 - bb * 392;
#pragma unroll
      for (int jt = 0; jt < 8; ++jt) {
        int colL = jt * 16 + l15;
        float bias = bqkv[s * 128 + colL];
        int hh = colL >> 5, dd = colL & 31;
        if (s == 2) {
          s16x4 o;
#pragma unroll
          for (int r = 0; r < 4; ++r) o[r] = (short)f2bf(acc[m][jt][r] + bias);
          *(s16x4*)&vtbuf[(((size_t)bb * 4 + hh) * 32 + dd) * NTOK + nn0] = o;
        } else {
          unsigned short* dst = (s == 0) ? qbuf : kbuf;
          float mul = (s == 0) ? SCALE : 1.0f;
#pragma unroll
          for (int r = 0; r < 4; ++r)
            dst[(((size_t)bb * 4 + hh) * NTOK + nn0 + r) * 32 + dd] =
                f2bf((acc[m][jt][r] + bias) * mul);
        }
      }
    }
  }
}

// ---------------- K3: attention (swapped QK^T) ----------------
__global__ __launch_bounds__(256, 4) void attn_kernel(
    const unsigned short* __restrict__ qbuf, const unsigned short* __restrict__ kbuf,
    const unsigned short* __restrict__ vtbuf, const unsigned short* __restrict__ biaspre,
    unsigned short* __restrict__ ctxbuf) {
  __shared__ unsigned short Ksh[400][40];   // 32.0 KB, keys x dh
  __shared__ unsigned int Psh[4][16][20];   // 5.1 KB per-wave P tiles

  const int tid = threadIdx.x;
  const int w = tid >> 6, lane = tid & 63;
  const int l15 = lane & 15, lhi = lane >> 4;
  const int bh = blockIdx.x;
  const int h = bh & 3, b = bh >> 2;
  const size_t base = (size_t)bh * (NTOK * 32);

  for (int i = tid; i < 3136; i += 256) {
    int row = i >> 3, c4 = i & 7;
    *(s16x4*)&Ksh[row][c4 * 4] = *(const s16x4*)(kbuf + base + (size_t)i * 4);
  }
  { int row = 392 + (tid >> 5); Ksh[row][tid & 31] = 0; }  // zero pad rows
  __syncthreads();

  const unsigned short* vbase = vtbuf + base;
  const s16x4* bias_lane =
      (const s16x4*)(biaspre + (size_t)h * 25 * 25 * 256 + (size_t)lane * 4);

  for (int rb = w; rb < 25; rb += 4) {
    int qrow = rb * 16 + l15; if (qrow > 391) qrow = 391;
    bf16x8 qf = *(const bf16x8*)(qbuf + base + (size_t)qrow * 32 + lhi * 8);
    const s16x4* bp = bias_lane + (size_t)rb * 25 * 64;  // +jt*64 per jt

    f32x4 o0 = 0.0f, o1 = 0.0f;
    float ssum = 0.f;

    for (int g = 0; g < 12; ++g) {  // jt pairs (2g, 2g+1), all k valid
      int jt0 = 2 * g, jt1 = 2 * g + 1;
      bf16x8 kf0 = *(const bf16x8*)&Ksh[jt0 * 16 + l15][lhi * 8];
      bf16x8 kf1 = *(const bf16x8*)&Ksh[jt1 * 16 + l15][lhi * 8];
      f32x4 s0 = __builtin_amdgcn_mfma_f32_16x16x32_bf16(kf0, qf, (f32x4)0.f, 0, 0, 0);
      f32x4 s1 = __builtin_amdgcn_mfma_f32_16x16x32_bf16(kf1, qf, (f32x4)0.f, 0, 0, 0);
      s16x4 bv0 = bp[jt0 * 64];
      s16x4 bv1 = bp[jt1 * 64];
      float e00 = __expf(s0[0] + b2f(bv0[0])), e01 = __expf(s0[1] + b2f(bv0[1]));
      float e02 = __expf(s0[2] + b2f(bv0[2])), e03 = __expf(s0[3] + b2f(bv0[3]));
      float e10 = __expf(s1[0] + b2f(bv1[0])), e11 = __expf(s1[1] + b2f(bv1[1]));
      float e12 = __expf(s1[2] + b2f(bv1[2])), e13 = __expf(s1[3] + b2f(bv1[3]));
      ssum += (e00 + e01 + e02 + e03) + (e10 + e11 + e12 + e13);
      u32x2 wlo; wlo[0] = pk2(e00, e01); wlo[1] = pk2(e02, e03);
      u32x2 whi; whi[0] = pk2(e10, e11); whi[1] = pk2(e12, e13);
      *(u32x2*)&Psh[w][l15][lhi * 2] = wlo;       // k cols lhi*4..+3
      *(u32x2*)&Psh[w][l15][8 + lhi * 2] = whi;   // k cols 16+lhi*4..+3
      bf16x8 pf = *(const bf16x8*)&Psh[w][l15][lhi * 4];
      bf16x8 vf0 = *(const bf16x8*)(vbase + (size_t)l15 * NTOK + g * 32 + lhi * 8);
      bf16x8 vf1 = *(const bf16x8*)(vbase + (size_t)(16 + l15) * NTOK + g * 32 + lhi * 8);
      o0 = __builtin_amdgcn_mfma_f32_16x16x32_bf16(pf, vf0, o0, 0, 0, 0);
      o1 = __builtin_amdgcn_mfma_f32_16x16x32_bf16(pf, vf1, o1, 0, 0, 0);
    }
    {  // g = 12: jt0 = 24 (k 384..391 valid only for lhi<2), jt1 absent
      bf16x8 kf0 = *(const bf16x8*)&Ksh[384 + l15][lhi * 8];
      f32x4 s0 = __builtin_amdgcn_mfma_f32_16x16x32_bf16(kf0, qf, (f32x4)0.f, 0, 0, 0);
      s16x4 bv0 = bp[24 * 64];
      float e00 = __expf(s0[0] + b2f(bv0[0])), e01 = __expf(s0[1] + b2f(bv0[1]));
      float e02 = __expf(s0[2] + b2f(bv0[2])), e03 = __expf(s0[3] + b2f(bv0[3]));
      if (lhi >= 2) { e00 = 0.f; e01 = 0.f; e02 = 0.f; e03 = 0.f; }
      ssum += (e00 + e01) + (e02 + e03);
      u32x2 wlo; wlo[0] = pk2(e00, e01); wlo[1] = pk2(e02, e03);
      u32x2 whi; whi[0] = 0u; whi[1] = 0u;
      *(u32x2*)&Psh[w][l15][lhi * 2] = wlo;
      *(u32x2*)&Psh[w][l15][8 + lhi * 2] = whi;
      bf16x8 pf = *(const bf16x8*)&Psh[w][l15][lhi * 4];
      bf16x8 vf0 = *(const bf16x8*)(vbase + (size_t)l15 * NTOK + 384 + lhi * 8);
      bf16x8 vf1 = *(const bf16x8*)(vbase + (size_t)(16 + l15) * NTOK + 384 + lhi * 8);
      o0 = __builtin_amdgcn_mfma_f32_16x16x32_bf16(pf, vf0, o0, 0, 0, 0);
      o1 = __builtin_amdgcn_mfma_f32_16x16x32_bf16(pf, vf1, o1, 0, 0, 0);
    }

    // total row sums: lanes sharing l15 (stride 16) hold partials
    ssum += __shfl_xor(ssum, 16);
    ssum += __shfl_xor(ssum, 32);
    float rtot = 1.f / ssum;   // valid for q-row = l15 (all lhi copies)
    float rr[4];
#pragma unroll
    for (int r = 0; r < 4; ++r) rr[r] = __shfl(rtot, lhi * 4 + r);

#pragma unroll
    for (int r = 0; r < 4; ++r) {
      int row = rb * 16 + lhi * 4 + r;
      if (row < NTOK) {
        unsigned short* crow = ctxbuf + ((size_t)(b * NTOK) + row) * 128 + h * 32;
        crow[l15] = f2bf(o0[r] * rr[r]);
        crow[16 + l15] = f2bf(o1[r] * rr[r]);
      }
    }
  }
}

// ---------------- K4: output projection — streaming, no LDS ----------------
__global__ __launch_bounds__(256, 4) void proj_kernel(
    const unsigned short* __restrict__ ctxbuf, const unsigned short* __restrict__ wpbf,
    const float* __restrict__ bp, float* __restrict__ out) {
  const int tid = threadIdx.x;
  const int w = tid >> 6, lane = tid & 63, l15 = lane & 15, lhi = lane >> 4;
  const int row0 = blockIdx.x * 128 + w * 32;

  bf16x8 af[2][4];
#pragma unroll
  for (int m = 0; m < 2; ++m)
#pragma unroll
    for (int kk = 0; kk < 4; ++kk)
      af[m][kk] = *(const bf16x8*)(
          ctxbuf + ((size_t)(row0 + m * 16 + l15)) * 128 + kk * 32 + lhi * 8);

  f32x4 acc[2][8];
#pragma unroll
  for (int m = 0; m < 2; ++m)
#pragma unroll
    for (int jt = 0; jt < 8; ++jt) acc[m][jt] = 0.0f;
#pragma unroll
  for (int kk = 0; kk < 4; ++kk) {
#pragma unroll
    for (int jt = 0; jt < 8; ++jt) {
      bf16x8 wf = *(const bf16x8*)(
          wpbf + ((size_t)(jt * 16 + l15)) * 128 + kk * 32 + lhi * 8);
      acc[0][jt] = __builtin_amdgcn_mfma_f32_16x16x32_bf16(af[0][kk], wf, acc[0][jt], 0, 0, 0);
      acc[1][jt] = __builtin_amdgcn_mfma_f32_16x16x32_bf16(af[1][kk], wf, acc[1][jt], 0, 0, 0);
    }
  }
#pragma unroll
  for (int m = 0; m < 2; ++m)
#pragma unroll
    for (int jt = 0; jt < 8; ++jt) {
      int colL = jt * 16 + l15;
      float bias = bp[colL];
#pragma unroll
      for (int r = 0; r < 4; ++r) {
        int t = row0 + m * 16 + lhi * 4 + r;
        out[(size_t)t * 128 + colL] = acc[m][jt][r] + bias;
      }
    }
}

// ---------------- launch ----------------
extern "C" void kernel_launch(void* const* d_in, const int* in_sizes, int n_in,
                              void* d_out, int out_size, void* d_ws, size_t ws_size,
                              hipStream_t stream) {
  const float* hidden = (const float*)d_in[0];
  const float* Wqkv = (const float*)d_in[1];
  const float* bqkv = (const float*)d_in[2];
  const float* Wp = (const float*)d_in[3];
  const float* bp = (const float*)d_in[4];
  const float* rpb = (const float*)d_in[5];
  const int* relidx = (const int*)d_in[6];

  // ws: q | k | vt(+pad) | ctx (bf16, 12,845,056 each) | biaspre | wq_bf | wp_bf
  unsigned short* qbuf = (unsigned short*)d_ws;
  unsigned short* kbuf = qbuf + 12845056;
  unsigned short* vtbuf = kbuf + 12845056;
  unsigned short* ctxbuf = vtbuf + 12845056 + 1024;  // pad: attn V reads overshoot
  unsigned short* biaspre = ctxbuf + 12845056;
  unsigned short* wqbf = biaspre + 640000;
  unsigned short* wpbf = wqbf + 49152;

  wcvt_kernel<<<64, 256, 0, stream>>>(Wqkv, Wp, wqbf, wpbf);
  biaspre_kernel<<<2500, 256, 0, stream>>>(rpb, relidx, biaspre);
  qkv_kernel<<<784, 256, 0, stream>>>(hidden, wqbf, bqkv, qbuf, kbuf, vtbuf);
  attn_kernel<<<1024, 256, 0, stream>>>(qbuf, kbuf, vtbuf, biaspre, ctxbuf);
  proj_kernel<<<784, 256, 0, stream>>>(ctxbuf, wpbf, bp, (float*)d_out);
}